// Round 4
// baseline (753.741 us; speedup 1.0000x reference)
//
#include <hip/hip_runtime.h>

// Problem constants (from reference): B=16, S=4096, D=256, MAXDUR=8
#define BATCH 16
#define SEQ   4096
#define DIM   256

#define WPB 8                                   // waves per block (512 threads)
#define SCAN_BLOCKS   BATCH                     // 16: one scan block per batch
#define SCATTER_BLOCKS (BATCH * SEQ / WPB)      // 8192: one wave per source row
#define TAILC 32                                // tail blocks per batch
#define TAIL_BLOCKS (BATCH * TAILC)             // 512
#define GRID (SCAN_BLOCKS + SCATTER_BLOCKS + TAIL_BLOCKS)

#define MAGIC 0x5ca9f1a6                        // != 0xAAAAAAAA ws poison

// native clang vector type — accepted by __builtin_nontemporal_{load,store}
typedef float f32x4 __attribute__((ext_vector_type(4)));

// ---------------------------------------------------------------------------
// Fused kernel.
//  blocks [0,16):            per-batch inclusive scan of durations -> csum,
//                            totals; publish flags[b] (agent-scope release).
//  blocks [16,16+8192):      scatter-expand, one wave per source row. Spin on
//                            flags[b] (relaxed + s_sleep), acquire, then read
//                            csum and store the row cnt times (independent
//                            predicated nontemporal stores).
//  remaining 512 blocks:     zero tail rows [totals[b], T).
// ---------------------------------------------------------------------------
__global__ __launch_bounds__(512) void expand_fused(const float* __restrict__ x,
                                                    const int* __restrict__ dims,
                                                    float* __restrict__ out,
                                                    int* __restrict__ csum,
                                                    int* __restrict__ totals,
                                                    int* __restrict__ flags,
                                                    int T) {
    const int tid  = threadIdx.x;
    const int lane = tid & 63;
    const int wave = tid >> 6;

    if (blockIdx.x < SCAN_BLOCKS) {
        // ----- scan batch b: 512 threads * 8 ints = 4096 -----
        __shared__ int wsum[WPB];
        const int b = blockIdx.x;
        const int4* src = (const int4*)(dims + b * SEQ);
        const int4 a0 = src[tid * 2];
        const int4 a1 = src[tid * 2 + 1];
        int p0 = a0.x, p1 = p0 + a0.y, p2 = p1 + a0.z, p3 = p2 + a0.w;
        int p4 = p3 + a1.x, p5 = p4 + a1.y, p6 = p5 + a1.z, p7 = p6 + a1.w;
        int v = p7;                               // thread total
        #pragma unroll
        for (int off = 1; off < 64; off <<= 1) {  // wave inclusive scan
            int n = __shfl_up(v, off, 64);
            if (lane >= off) v += n;
        }
        if (lane == 63) wsum[wave] = v;
        __syncthreads();
        if (tid == 0) {
            int run = 0;
            #pragma unroll
            for (int i = 0; i < WPB; ++i) { int t = wsum[i]; wsum[i] = run; run += t; }
            totals[b] = run;
        }
        __syncthreads();
        const int excl = wsum[wave] + (v - p7);
        int4 o0, o1;
        o0.x = excl + p0; o0.y = excl + p1; o0.z = excl + p2; o0.w = excl + p3;
        o1.x = excl + p4; o1.y = excl + p5; o1.z = excl + p6; o1.w = excl + p7;
        ((int4*)(csum + b * SEQ))[tid * 2]     = o0;
        ((int4*)(csum + b * SEQ))[tid * 2 + 1] = o1;
        __syncthreads();                          // all csum/totals writes done
        if (tid == 0)
            __hip_atomic_store(flags + b, MAGIC, __ATOMIC_RELEASE,
                               __HIP_MEMORY_SCOPE_AGENT);
    } else if (blockIdx.x < SCAN_BLOCKS + SCATTER_BLOCKS) {
        // ----- scatter: one wave per source row (b,s) -----
        const int wv = (blockIdx.x - SCAN_BLOCKS) * WPB + wave;  // 0..B*S-1
        const int b  = wv >> 12;                                 // / SEQ
        const int s  = wv & (SEQ - 1);
        while (__hip_atomic_load(flags + b, __ATOMIC_RELAXED,
                                 __HIP_MEMORY_SCOPE_AGENT) != MAGIC)
            __builtin_amdgcn_s_sleep(8);
        (void)__hip_atomic_load(flags + b, __ATOMIC_ACQUIRE,
                                __HIP_MEMORY_SCOPE_AGENT);
        const int end   = csum[wv];
        const int start = (s == 0) ? 0 : csum[wv - 1];
        const int cnt   = end - start;            // 0..7, wave-uniform
        if (cnt <= 0) return;
        const f32x4 row = __builtin_nontemporal_load(
            ((const f32x4*)x) + (size_t)wv * (DIM / 4) + lane);
        f32x4* dst = (f32x4*)out + ((size_t)b * T + start) * (DIM / 4) + lane;
        #pragma unroll
        for (int j = 0; j < 7; ++j) {             // independent predicated stores
            if (j < cnt) __builtin_nontemporal_store(row, dst + j * (DIM / 4));
        }
        for (int j = 7; j < cnt; ++j)             // safety net (MAXDUR>8)
            __builtin_nontemporal_store(row, dst + j * (DIM / 4));
    } else {
        // ----- tail zero-fill: rows [totals[b], T) -----
        const int idx   = blockIdx.x - SCAN_BLOCKS - SCATTER_BLOCKS;
        const int b     = idx / TAILC;
        const int chunk = idx % TAILC;
        while (__hip_atomic_load(flags + b, __ATOMIC_RELAXED,
                                 __HIP_MEMORY_SCOPE_AGENT) != MAGIC)
            __builtin_amdgcn_s_sleep(8);
        (void)__hip_atomic_load(flags + b, __ATOMIC_ACQUIRE,
                                __HIP_MEMORY_SCOPE_AGENT);
        const int t0 = totals[b];
        const f32x4 z = {0.f, 0.f, 0.f, 0.f};
        for (int t = t0 + chunk * WPB + wave; t < T; t += TAILC * WPB)
            __builtin_nontemporal_store(
                z, (f32x4*)out + ((size_t)b * T + t) * (DIM / 4) + lane);
    }
}

extern "C" void kernel_launch(void* const* d_in, const int* in_sizes, int n_in,
                              void* d_out, int out_size, void* d_ws, size_t ws_size,
                              hipStream_t stream) {
    const float* x    = (const float*)d_in[0];   // [B,S,D] float32
    const int*   dims = (const int*)d_in[1];     // [B,S,1] int32
    float*       out  = (float*)d_out;           // [B,T,D] float32

    const int T = out_size / (BATCH * DIM);      // padded output length

    int* flags  = (int*)d_ws;                    // 16 ints (poisoned 0xAA.. each call)
    int* totals = flags + 16;                    // 16 ints
    int* csum   = (int*)((char*)d_ws + 256);     // B*S ints, 16B-aligned

    expand_fused<<<GRID, 512, 0, stream>>>(x, dims, out, csum, totals, flags, T);
}

// Round 5
// 282.323 us; speedup vs baseline: 2.6698x; 2.6698x over previous
//
#include <hip/hip_runtime.h>

// Problem constants (from reference): B=16, S=4096, D=256, MAXDUR=8
#define BATCH 16
#define SEQ   4096
#define DIM   256

#define SCATTER_BLOCKS (BATCH * SEQ / 4)   // 4 waves/block, 1 wave per source row
#define TAILC 128                          // tail-zero blocks per batch

// native clang vector type — accepted by __builtin_nontemporal_{load,store}
typedef float f32x4 __attribute__((ext_vector_type(4)));

// ---------------------------------------------------------------------------
// Kernel A: per-batch inclusive scan of durations -> csum[B*S], totals[B]
// One block per batch; 1024 threads * 4 elements = 4096.
// ---------------------------------------------------------------------------
__global__ __launch_bounds__(1024) void scan_kernel(const int* __restrict__ dims,
                                                    int* __restrict__ csum,
                                                    int* __restrict__ totals) {
    __shared__ int wsum[16];
    const int b    = blockIdx.x;
    const int tid  = threadIdx.x;      // 0..1023
    const int lane = tid & 63;
    const int wave = tid >> 6;         // 0..15

    // 4 consecutive durations per thread (int4, 16B aligned)
    const int4 dv = ((const int4*)(dims + b * SEQ))[tid];
    const int p0 = dv.x;
    const int p1 = p0 + dv.y;
    const int p2 = p1 + dv.z;
    const int p3 = p2 + dv.w;          // thread-local inclusive sums
    int v = p3;                        // thread total

    // wave-level inclusive scan of thread totals (64 lanes)
    #pragma unroll
    for (int off = 1; off < 64; off <<= 1) {
        int n = __shfl_up(v, off, 64);
        if (lane >= off) v += n;
    }
    if (lane == 63) wsum[wave] = v;    // wave total
    __syncthreads();

    if (tid == 0) {                    // serial exclusive scan over 16 wave totals
        int run = 0;
        #pragma unroll
        for (int i = 0; i < 16; ++i) { int t = wsum[i]; wsum[i] = run; run += t; }
        totals[b] = run;               // full batch total
    }
    __syncthreads();

    const int excl = wsum[wave] + (v - p3);   // block-exclusive prefix of this thread
    int4 o;
    o.x = excl + p0; o.y = excl + p1; o.z = excl + p2; o.w = excl + p3;
    // cached store (NOT nontemporal): consumed by expand_kernel right after
    ((int4*)(csum + b * SEQ))[tid] = o;
}

// ---------------------------------------------------------------------------
// Kernel B: scatter-expand + tail zero-fill.
// Blocks [0, SCATTER_BLOCKS): one wave per source row (b,s). Reads the
//   256-float row once (f32x4/lane = one 1KB wave store per row copy) and
//   stores it cnt times to consecutive output rows as 7 INDEPENDENT
//   predicated nontemporal stores (cnt wave-uniform -> s_cbranch).
// Blocks [SCATTER_BLOCKS, +B*TAILC): zero rows [totals[b], T).
// ---------------------------------------------------------------------------
__global__ __launch_bounds__(256) void expand_kernel(const float* __restrict__ x,
                                                     const int* __restrict__ csum,
                                                     const int* __restrict__ totals,
                                                     float* __restrict__ out,
                                                     int T) {
    const int lane = threadIdx.x & 63;
    const int wave = threadIdx.x >> 6;

    if (blockIdx.x < SCATTER_BLOCKS) {
        const int wv  = blockIdx.x * 4 + wave;    // global source-row id, 0..B*S-1
        const int b   = wv >> 12;                 // / SEQ
        const int s   = wv & (SEQ - 1);

        int start, end;
        if (s != 0) {                             // one int2 load: {csum[wv-1], csum[wv]}
            const int2 se = *(const int2*)(csum + wv - 1);
            start = se.x; end = se.y;
        } else {
            start = 0;   end = csum[wv];
        }
        const int cnt = end - start;              // 0..7, wave-uniform
        if (cnt <= 0) return;

        const f32x4 row = __builtin_nontemporal_load(
            ((const f32x4*)x) + (size_t)wv * (DIM / 4) + lane);
        f32x4* dst = (f32x4*)out + ((size_t)b * T + start) * (DIM / 4) + lane;

        #pragma unroll
        for (int j = 0; j < 7; ++j) {             // independent predicated stores
            if (j < cnt) __builtin_nontemporal_store(row, dst + j * (DIM / 4));
        }
        for (int j = 7; j < cnt; ++j)             // safety net if MAXDUR ever > 8
            __builtin_nontemporal_store(row, dst + j * (DIM / 4));
    } else {
        const int idx   = blockIdx.x - SCATTER_BLOCKS;
        const int b     = idx / TAILC;
        const int chunk = idx % TAILC;
        const int t0    = totals[b];
        const f32x4 z   = {0.f, 0.f, 0.f, 0.f};
        // TAILC blocks * 4 waves stride over tail rows of batch b, 2x unrolled
        for (int t = t0 + chunk * 4 + wave; t < T; t += 2 * TAILC * 4) {
            __builtin_nontemporal_store(
                z, (f32x4*)out + ((size_t)b * T + t) * (DIM / 4) + lane);
            const int t2 = t + TAILC * 4;
            if (t2 < T)
                __builtin_nontemporal_store(
                    z, (f32x4*)out + ((size_t)b * T + t2) * (DIM / 4) + lane);
        }
    }
}

extern "C" void kernel_launch(void* const* d_in, const int* in_sizes, int n_in,
                              void* d_out, int out_size, void* d_ws, size_t ws_size,
                              hipStream_t stream) {
    const float* x    = (const float*)d_in[0];   // [B,S,D] float32
    const int*   dims = (const int*)d_in[1];     // [B,S,1] int32
    float*       out  = (float*)d_out;           // [B,T,D] float32

    const int T = out_size / (BATCH * DIM);      // padded output length

    int* totals = (int*)d_ws;                    // B ints
    int* csum   = totals + 64;                   // 256B offset keeps 16B alignment

    scan_kernel<<<BATCH, 1024, 0, stream>>>(dims, csum, totals);
    expand_kernel<<<SCATTER_BLOCKS + BATCH * TAILC, 256, 0, stream>>>(
        x, csum, totals, out, T);
}